// Round 1
// baseline (648.734 us; speedup 1.0000x reference)
//
#include <hip/hip_runtime.h>
#include <hip/hip_fp16.h>

#define TLEN 512
#define HDIM 32
#define FOUT 20

typedef __attribute__((ext_vector_type(8))) short bf16x8;
typedef __attribute__((ext_vector_type(4))) float f32x4;

__device__ __forceinline__ float sigm(float v) {
  float e = __builtin_amdgcn_exp2f(-1.4426950408889634f * v);
  return __builtin_amdgcn_rcpf(1.0f + e);
}
__device__ __forceinline__ float tanh_f(float v) {
  float e = __builtin_amdgcn_exp2f(2.8853900817779268f * v);
  return 1.0f - 2.0f * __builtin_amdgcn_rcpf(1.0f + e);
}
// round-to-nearest-even bf16 hi/lo split: v ~= hi + lo with ~16-bit mantissa coverage
__device__ __forceinline__ void hilo(float v, short& h, short& l) {
  unsigned u = __builtin_bit_cast(unsigned, v);
  unsigned r = u + 0x7fffu + ((u >> 16) & 1u);
  h = (short)(r >> 16);
  float hf = __builtin_bit_cast(float, r & 0xffff0000u);
  float res = v - hf;
  unsigned u2 = __builtin_bit_cast(unsigned, res);
  unsigned r2 = u2 + 0x7fffu + ((u2 >> 16) & 1u);
  l = (short)(r2 >> 16);
}

// Block: 512 threads = 8 waves, handles 16 batch rows for all T.
// Wave w owns gate-tile w (gate cols 16w..16w+15). 256 blocks -> 1 block/CU, 2 waves/SIMD.
__global__ __launch_bounds__(512, 2) void lstm_seq_kernel(
    const float* __restrict__ xg,
    const float* __restrict__ Wih1, const float* __restrict__ Whh1,
    const float* __restrict__ bih1, const float* __restrict__ bhh1,
    const float* __restrict__ Wih2, const float* __restrict__ Whh2,
    const float* __restrict__ bih2, const float* __restrict__ bhh2,
    const float* __restrict__ Wout, const float* __restrict__ bout,
    float* __restrict__ out)
{
  __shared__ float gbuf[16 * 132];                 // gates exchange, stride 132 (2-way max)
  __shared__ short h1hi[16 * 40], h1lo[16 * 40];   // h rows, stride 40 halfwords
  __shared__ short h2hi[16 * 40], h2lo[16 * 40];
  __shared__ __half xl[16 * 1028];                 // x staged as fp16, stride 1028 halfwords

  const int tid  = threadIdx.x;
  const int w    = tid >> 6;     // wave 0..7
  const int lane = tid & 63;
  const int n    = lane & 15;    // frag col (N) / A-row (M)
  const int q    = lane >> 4;    // quad
  const int q4   = q * 4;
  const int q8   = q * 8;
  const int b0   = blockIdx.x * 16;

  // ---- stage x[b0..b0+15][0..T*2) into LDS as fp16 (coalesced)
  for (int idx = tid; idx < 16 * 1024; idx += 512) {
    int row = idx >> 10, col = idx & 1023;
    xl[row * 1028 + col] = __float2half(xg[((size_t)(b0 + row) << 10) + col]);
  }

  // ---- per-wave weight B-fragments (hi/lo bf16), register-resident
  const int gcol = 16 * w + n;   // this lane's gate column within 0..127
  bf16x8 Whh1h, Whh1l, Wih2h, Wih2l, Whh2h, Whh2l;
  #pragma unroll
  for (int j = 0; j < 8; j++) {
    short hh, ll;
    hilo(Whh1[gcol * HDIM + q8 + j], hh, ll); Whh1h[j] = hh; Whh1l[j] = ll;
    hilo(Wih2[gcol * HDIM + q8 + j], hh, ll); Wih2h[j] = hh; Wih2l[j] = ll;
    hilo(Whh2[gcol * HDIM + q8 + j], hh, ll); Whh2h[j] = hh; Whh2l[j] = ll;
  }
  const float b1v = bih1[gcol] + bhh1[gcol];
  const float b2v = bih2[gcol] + bhh2[gcol];
  const float wx0 = Wih1[gcol * 2 + 0];
  const float wx1 = Wih1[gcol * 2 + 1];

  bf16x8 WoH = {0,0,0,0,0,0,0,0}, WoL = {0,0,0,0,0,0,0,0};
  float bov = 0.0f;
  if (w < 2 && gcol < FOUT) {
    #pragma unroll
    for (int j = 0; j < 8; j++) {
      short hh, ll;
      hilo(Wout[gcol * HDIM + q8 + j], hh, ll); WoH[j] = hh; WoL[j] = ll;
    }
    bov = bout[gcol];
  }

  // update-phase mapping: wave w handles rows 2w, 2w+1; 1 (row,col) position per lane
  const int urow  = 2 * w + (lane >> 5);
  const int ucol  = lane & 31;
  const int ubase = urow * 132 + ucol;
  const int hoff  = urow * 40 + ucol;
  const int aoff  = n * 40 + q8;       // A-frag read: row n, k-chunk q
  float c1 = 0.0f, c2 = 0.0f;

  bf16x8 h1Ah = {0,0,0,0,0,0,0,0}, h1Al = {0,0,0,0,0,0,0,0};
  bf16x8 h2Ah = {0,0,0,0,0,0,0,0}, h2Al = {0,0,0,0,0,0,0,0};

  __syncthreads();

  for (int t = 0; t < TLEN; ++t) {
    // x for C-frag rows q4..q4+3 (LDS broadcast reads)
    float2 xc[4];
    #pragma unroll
    for (int r = 0; r < 4; r++) {
      __half2 hv = *(const __half2*)&xl[(q4 + r) * 1028 + 2 * t];
      xc[r].x = __half2float(hv.x);
      xc[r].y = __half2float(hv.y);
    }

    // ---- layer-1 gates (tile w): b1 + x@Wih1^T (VALU, fp32) + h1@Whh1^T (3-product MFMA)
    f32x4 acc;
    #pragma unroll
    for (int r = 0; r < 4; r++) acc[r] = fmaf(xc[r].y, wx1, fmaf(xc[r].x, wx0, b1v));
    acc = __builtin_amdgcn_mfma_f32_16x16x32_bf16(h1Ah, Whh1h, acc, 0, 0, 0);
    acc = __builtin_amdgcn_mfma_f32_16x16x32_bf16(h1Al, Whh1h, acc, 0, 0, 0);
    acc = __builtin_amdgcn_mfma_f32_16x16x32_bf16(h1Ah, Whh1l, acc, 0, 0, 0);
    #pragma unroll
    for (int r = 0; r < 4; r++) gbuf[(q4 + r) * 132 + gcol] = acc[r];
    __syncthreads();  // bar1: gates1 visible

    // ---- layer-1 pointwise update (rows 2w,2w+1)
    {
      float gi = gbuf[ubase], gf = gbuf[ubase + 32], gg = gbuf[ubase + 64], go = gbuf[ubase + 96];
      float iv = sigm(gi), fv = sigm(gf), gv = tanh_f(gg), ov = sigm(go);
      c1 = fv * c1 + iv * gv;
      float hv = ov * tanh_f(c1);
      short hh, ll; hilo(hv, hh, ll);
      h1hi[hoff] = hh; h1lo[hoff] = ll;
    }
    __syncthreads();  // bar2: h1(t) visible
    h1Ah = *(const bf16x8*)&h1hi[aoff];
    h1Al = *(const bf16x8*)&h1lo[aoff];

    // ---- layer-2 gates (tile w): b2 + h1@Wih2^T + h2@Whh2^T
    f32x4 acc2;
    #pragma unroll
    for (int r = 0; r < 4; r++) acc2[r] = b2v;
    acc2 = __builtin_amdgcn_mfma_f32_16x16x32_bf16(h1Ah, Wih2h, acc2, 0, 0, 0);
    acc2 = __builtin_amdgcn_mfma_f32_16x16x32_bf16(h1Al, Wih2h, acc2, 0, 0, 0);
    acc2 = __builtin_amdgcn_mfma_f32_16x16x32_bf16(h1Ah, Wih2l, acc2, 0, 0, 0);
    acc2 = __builtin_amdgcn_mfma_f32_16x16x32_bf16(h2Ah, Whh2h, acc2, 0, 0, 0);
    acc2 = __builtin_amdgcn_mfma_f32_16x16x32_bf16(h2Al, Whh2h, acc2, 0, 0, 0);
    acc2 = __builtin_amdgcn_mfma_f32_16x16x32_bf16(h2Ah, Whh2l, acc2, 0, 0, 0);
    #pragma unroll
    for (int r = 0; r < 4; r++) gbuf[(q4 + r) * 132 + gcol] = acc2[r];
    __syncthreads();  // bar3: gates2 visible

    // ---- layer-2 pointwise update
    {
      float gi = gbuf[ubase], gf = gbuf[ubase + 32], gg = gbuf[ubase + 64], go = gbuf[ubase + 96];
      float iv = sigm(gi), fv = sigm(gf), gv = tanh_f(gg), ov = sigm(go);
      c2 = fv * c2 + iv * gv;
      float hv = ov * tanh_f(c2);
      short hh, ll; hilo(hv, hh, ll);
      h2hi[hoff] = hh; h2lo[hoff] = ll;
    }
    __syncthreads();  // bar4: h2(t) visible
    h2Ah = *(const bf16x8*)&h2hi[aoff];
    h2Al = *(const bf16x8*)&h2lo[aoff];

    // ---- output projection: out = h2 @ Wout^T + bout  (waves 0,1; cols 0..19)
    if (w < 2) {
      f32x4 ao;
      #pragma unroll
      for (int r = 0; r < 4; r++) ao[r] = bov;
      ao = __builtin_amdgcn_mfma_f32_16x16x32_bf16(h2Ah, WoH, ao, 0, 0, 0);
      ao = __builtin_amdgcn_mfma_f32_16x16x32_bf16(h2Al, WoH, ao, 0, 0, 0);
      ao = __builtin_amdgcn_mfma_f32_16x16x32_bf16(h2Ah, WoL, ao, 0, 0, 0);
      if (gcol < FOUT) {
        #pragma unroll
        for (int r = 0; r < 4; r++)
          out[((size_t)(b0 + q4 + r) * TLEN + t) * FOUT + gcol] = ao[r];
      }
    }
  }
}

extern "C" void kernel_launch(void* const* d_in, const int* in_sizes, int n_in,
                              void* d_out, int out_size, void* d_ws, size_t ws_size,
                              hipStream_t stream) {
  const float* xg   = (const float*)d_in[0];
  const float* Wih1 = (const float*)d_in[1];
  const float* Whh1 = (const float*)d_in[2];
  const float* bih1 = (const float*)d_in[3];
  const float* bhh1 = (const float*)d_in[4];
  const float* Wih2 = (const float*)d_in[5];
  const float* Whh2 = (const float*)d_in[6];
  const float* bih2 = (const float*)d_in[7];
  const float* bhh2 = (const float*)d_in[8];
  const float* Wout = (const float*)d_in[9];
  const float* bout = (const float*)d_in[10];
  float* out = (float*)d_out;

  hipLaunchKernelGGL(lstm_seq_kernel, dim3(256), dim3(512), 0, stream,
                     xg, Wih1, Whh1, bih1, bhh1, Wih2, Whh2, bih2, bhh2, Wout, bout, out);
}

// Round 2
// 563.241 us; speedup vs baseline: 1.1518x; 1.1518x over previous
//
#include <hip/hip_runtime.h>
#include <hip/hip_fp16.h>

#define TLEN 512
#define HDIM 32
#define FOUT 20

typedef __attribute__((ext_vector_type(8))) short bf16x8;
typedef __attribute__((ext_vector_type(4))) float f32x4;

__device__ __forceinline__ float sigm(float v) {
  float e = __builtin_amdgcn_exp2f(-1.4426950408889634f * v);
  return __builtin_amdgcn_rcpf(1.0f + e);
}
__device__ __forceinline__ float tanh_f(float v) {
  float e = __builtin_amdgcn_exp2f(2.8853900817779268f * v);
  return 1.0f - 2.0f * __builtin_amdgcn_rcpf(1.0f + e);
}
// round-to-nearest-even bf16 hi/lo split: v ~= hi + lo (~16-bit mantissa coverage)
__device__ __forceinline__ void hilo(float v, short& h, short& l) {
  unsigned u = __builtin_bit_cast(unsigned, v);
  unsigned r = u + 0x7fffu + ((u >> 16) & 1u);
  h = (short)(r >> 16);
  float hf = __builtin_bit_cast(float, r & 0xffff0000u);
  float res = v - hf;
  unsigned u2 = __builtin_bit_cast(unsigned, res);
  unsigned r2 = u2 + 0x7fffu + ((u2 >> 16) & 1u);
  l = (short)(r2 >> 16);
}

// DPP quad-perm cross-lane moves (single-cycle VALU, no LDS)
__device__ __forceinline__ float dpp_xor1(float x) {  // quad_perm [1,0,3,2]
  return __builtin_bit_cast(float,
      __builtin_amdgcn_mov_dpp(__builtin_bit_cast(int, x), 0xB1, 0xF, 0xF, true));
}
__device__ __forceinline__ float dpp_xor2(float x) {  // quad_perm [2,3,0,1]
  return __builtin_bit_cast(float,
      __builtin_amdgcn_mov_dpp(__builtin_bit_cast(int, x), 0x4E, 0xF, 0xF, true));
}

// Barrier that only drains LDS (lgkmcnt) — avoids __syncthreads()'s
// s_waitcnt vmcnt(0), which would serialize on the in-flight output stores.
__device__ __forceinline__ void barrier_lgkm() {
  asm volatile("s_waitcnt lgkmcnt(0)\n\ts_barrier" ::: "memory");
}

// Block: 512 threads = 8 waves, 16 batch rows for all T. 256 blocks = 1/CU.
// Gate columns are INTERLEAVED: MFMA col c = (unit c>>2, gate c&3), so the
// 4 gates of one (unit,row) sit in a 4-lane x 4-reg square of the C fragment
// -> DPP 4x4 transpose makes the pointwise update lane-local (no gbuf LDS,
// no barrier). Only h needs a cross-wave LDS round trip (2 barriers/step).
__global__ __launch_bounds__(512, 2) void lstm_seq_kernel(
    const float* __restrict__ xg,
    const float* __restrict__ Wih1, const float* __restrict__ Whh1,
    const float* __restrict__ bih1, const float* __restrict__ bhh1,
    const float* __restrict__ Wih2, const float* __restrict__ Whh2,
    const float* __restrict__ bih2, const float* __restrict__ bhh2,
    const float* __restrict__ Wout, const float* __restrict__ bout,
    float* __restrict__ out)
{
  __shared__ __half xl[16 * 1028];                 // x staged fp16, stride 1028
  __shared__ short h1hi[16 * 40], h1lo[16 * 40];   // h rows, stride 40 halfwords
  __shared__ short h2hi[16 * 40], h2lo[16 * 40];

  const int tid  = threadIdx.x;
  const int w    = tid >> 6;     // wave 0..7
  const int lane = tid & 63;
  const int n    = lane & 15;    // frag col (N) / A-row (M)
  const int q    = lane >> 4;    // quad
  const int q4   = q * 4;
  const int q8   = q * 8;
  const int b0   = blockIdx.x * 16;

  // ---- stage x[b0..b0+15][0..1024) into LDS as fp16 (coalesced)
  for (int idx = tid; idx < 16 * 1024; idx += 512) {
    int row = idx >> 10, col = idx & 1023;
    xl[row * 1028 + col] = __float2half(xg[((size_t)(b0 + row) << 10) + col]);
  }

  // ---- per-wave weight B-fragments, gate-interleaved column mapping:
  // tile col n -> unit 4w+(n>>2), gate n&3; original gate row:
  const int og = (n & 3) * HDIM + 4 * w + (n >> 2);
  bf16x8 Whh1h, Whh1l, Wih2h, Wih2l, Whh2h, Whh2l;
  #pragma unroll
  for (int j = 0; j < 8; j++) {
    short hh, ll;
    hilo(Whh1[og * HDIM + q8 + j], hh, ll); Whh1h[j] = hh; Whh1l[j] = ll;
    hilo(Wih2[og * HDIM + q8 + j], hh, ll); Wih2h[j] = hh; Wih2l[j] = ll;
    hilo(Whh2[og * HDIM + q8 + j], hh, ll); Whh2h[j] = hh; Whh2l[j] = ll;
  }
  const float b1v = bih1[og] + bhh1[og];
  const float b2v = bih2[og] + bhh2[og];
  const float wx0 = Wih1[og * 2 + 0];
  const float wx1 = Wih1[og * 2 + 1];

  // ---- out-projection fragment (natural cols 0..19, waves 0,1)
  const int ocol = 16 * w + n;
  bf16x8 WoH = {0,0,0,0,0,0,0,0}, WoL = {0,0,0,0,0,0,0,0};
  float bov = 0.0f;
  if (w < 2 && ocol < FOUT) {
    #pragma unroll
    for (int j = 0; j < 8; j++) {
      short hh, ll;
      hilo(Wout[ocol * HDIM + q8 + j], hh, ll); WoH[j] = hh; WoL[j] = ll;
    }
    bov = bout[ocol];
  }

  // lane-local LSTM state position: unit 4w+(n>>2), row q4+(n&3)
  const int hoff = (q4 + (n & 3)) * 40 + 4 * w + (n >> 2);
  const int aoff = n * 40 + q8;       // A-frag read: row n, k-chunk q
  float c1 = 0.0f, c2 = 0.0f;

  bf16x8 h1Ah = {0,0,0,0,0,0,0,0}, h1Al = {0,0,0,0,0,0,0,0};
  bf16x8 h2Ah = {0,0,0,0,0,0,0,0}, h2Al = {0,0,0,0,0,0,0,0};

  __syncthreads();   // full barrier once: x staging visible

  // prefetch x(t=0) for C-frag rows q4..q4+3
  float2 xc[4];
  #pragma unroll
  for (int r = 0; r < 4; r++) {
    __half2 hv = *(const __half2*)&xl[(q4 + r) * 1028];
    xc[r].x = __half2float(hv.x);
    xc[r].y = __half2float(hv.y);
  }

  for (int t = 0; t < TLEN; ++t) {
    // ---- layer-1 gates: b1 + x@Wih1^T (VALU fp32) + h1@Whh1^T (3-prod MFMA)
    f32x4 acc;
    #pragma unroll
    for (int r = 0; r < 4; r++) acc[r] = fmaf(xc[r].y, wx1, fmaf(xc[r].x, wx0, b1v));
    acc = __builtin_amdgcn_mfma_f32_16x16x32_bf16(h1Ah, Whh1h, acc, 0, 0, 0);
    acc = __builtin_amdgcn_mfma_f32_16x16x32_bf16(h1Al, Whh1h, acc, 0, 0, 0);
    acc = __builtin_amdgcn_mfma_f32_16x16x32_bf16(h1Ah, Whh1l, acc, 0, 0, 0);

    // prefetch next x (independent; hides LDS latency)
    {
      int tn = (t + 1 < TLEN) ? t + 1 : t;
      #pragma unroll
      for (int r = 0; r < 4; r++) {
        __half2 hv = *(const __half2*)&xl[(q4 + r) * 1028 + 2 * tn];
        xc[r].x = __half2float(hv.x);
        xc[r].y = __half2float(hv.y);
      }
    }

    // ---- 4x4 DPP transpose within 4-lane groups: regs become {i,f,g,o}
    {
      float t0 = dpp_xor1(acc[0]), t1 = dpp_xor1(acc[1]),
            t2 = dpp_xor1(acc[2]), t3 = dpp_xor1(acc[3]);
      bool o1 = (n & 1);
      float s0 = o1 ? t1 : acc[0];
      float s1 = o1 ? acc[1] : t0;
      float s2 = o1 ? t3 : acc[2];
      float s3 = o1 ? acc[3] : t2;
      float u0 = dpp_xor2(s0), u1 = dpp_xor2(s1),
            u2 = dpp_xor2(s2), u3 = dpp_xor2(s3);
      bool o2 = (n & 2);
      float gi = o2 ? u2 : s0;
      float gf = o2 ? u3 : s1;
      float gg = o2 ? s2 : u0;
      float go = o2 ? s3 : u1;
      // ---- layer-1 lane-local update
      float iv = sigm(gi), fv = sigm(gf), gv = tanh_f(gg), ov = sigm(go);
      c1 = fv * c1 + iv * gv;
      float hv = ov * tanh_f(c1);
      short hh, ll; hilo(hv, hh, ll);
      h1hi[hoff] = hh; h1lo[hoff] = ll;
    }
    barrier_lgkm();   // h1(t) visible
    h1Ah = *(const bf16x8*)&h1hi[aoff];
    h1Al = *(const bf16x8*)&h1lo[aoff];

    // ---- layer-2 gates: two independent 3-MFMA chains
    f32x4 a2a, a2b;
    #pragma unroll
    for (int r = 0; r < 4; r++) { a2a[r] = b2v; a2b[r] = 0.0f; }
    a2a = __builtin_amdgcn_mfma_f32_16x16x32_bf16(h1Ah, Wih2h, a2a, 0, 0, 0);
    a2b = __builtin_amdgcn_mfma_f32_16x16x32_bf16(h2Ah, Whh2h, a2b, 0, 0, 0);
    a2a = __builtin_amdgcn_mfma_f32_16x16x32_bf16(h1Al, Wih2h, a2a, 0, 0, 0);
    a2b = __builtin_amdgcn_mfma_f32_16x16x32_bf16(h2Al, Whh2h, a2b, 0, 0, 0);
    a2a = __builtin_amdgcn_mfma_f32_16x16x32_bf16(h1Ah, Wih2l, a2a, 0, 0, 0);
    a2b = __builtin_amdgcn_mfma_f32_16x16x32_bf16(h2Ah, Whh2l, a2b, 0, 0, 0);
    #pragma unroll
    for (int r = 0; r < 4; r++) a2a[r] += a2b[r];

    // ---- transpose + layer-2 update
    {
      float t0 = dpp_xor1(a2a[0]), t1 = dpp_xor1(a2a[1]),
            t2 = dpp_xor1(a2a[2]), t3 = dpp_xor1(a2a[3]);
      bool o1 = (n & 1);
      float s0 = o1 ? t1 : a2a[0];
      float s1 = o1 ? a2a[1] : t0;
      float s2 = o1 ? t3 : a2a[2];
      float s3 = o1 ? a2a[3] : t2;
      float u0 = dpp_xor2(s0), u1 = dpp_xor2(s1),
            u2 = dpp_xor2(s2), u3 = dpp_xor2(s3);
      bool o2 = (n & 2);
      float gi = o2 ? u2 : s0;
      float gf = o2 ? u3 : s1;
      float gg = o2 ? s2 : u0;
      float go = o2 ? s3 : u1;
      float iv = sigm(gi), fv = sigm(gf), gv = tanh_f(gg), ov = sigm(go);
      c2 = fv * c2 + iv * gv;
      float hv = ov * tanh_f(c2);
      short hh, ll; hilo(hv, hh, ll);
      h2hi[hoff] = hh; h2lo[hoff] = ll;
    }
    barrier_lgkm();   // h2(t) visible
    h2Ah = *(const bf16x8*)&h2hi[aoff];
    h2Al = *(const bf16x8*)&h2lo[aoff];

    // ---- output projection (waves 0,1; cols 0..19); stores never block:
    // barriers only wait lgkmcnt, so vmem stores drain in the background
    if (w < 2) {
      f32x4 ao;
      #pragma unroll
      for (int r = 0; r < 4; r++) ao[r] = bov;
      ao = __builtin_amdgcn_mfma_f32_16x16x32_bf16(h2Ah, WoH, ao, 0, 0, 0);
      ao = __builtin_amdgcn_mfma_f32_16x16x32_bf16(h2Al, WoH, ao, 0, 0, 0);
      ao = __builtin_amdgcn_mfma_f32_16x16x32_bf16(h2Ah, WoL, ao, 0, 0, 0);
      if (ocol < FOUT) {
        #pragma unroll
        for (int r = 0; r < 4; r++)
          out[((size_t)(b0 + q4 + r) * TLEN + t) * FOUT + ocol] = ao[r];
      }
    }
  }
}

extern "C" void kernel_launch(void* const* d_in, const int* in_sizes, int n_in,
                              void* d_out, int out_size, void* d_ws, size_t ws_size,
                              hipStream_t stream) {
  const float* xg   = (const float*)d_in[0];
  const float* Wih1 = (const float*)d_in[1];
  const float* Whh1 = (const float*)d_in[2];
  const float* bih1 = (const float*)d_in[3];
  const float* bhh1 = (const float*)d_in[4];
  const float* Wih2 = (const float*)d_in[5];
  const float* Whh2 = (const float*)d_in[6];
  const float* bih2 = (const float*)d_in[7];
  const float* bhh2 = (const float*)d_in[8];
  const float* Wout = (const float*)d_in[9];
  const float* bout = (const float*)d_in[10];
  float* out = (float*)d_out;

  hipLaunchKernelGGL(lstm_seq_kernel, dim3(256), dim3(512), 0, stream,
                     xg, Wih1, Whh1, bih1, bhh1, Wih2, Whh2, bih2, bhh2, Wout, bout, out);
}

// Round 3
// 502.120 us; speedup vs baseline: 1.2920x; 1.1217x over previous
//
#include <hip/hip_runtime.h>
#include <hip/hip_fp16.h>

#define TLEN 512
#define HDIM 32
#define FOUT 20
#define HST  36   // h row stride in halfwords (72B = 18 dwords; gcd(18,32)=2 -> <=4-way on b64 reads)

typedef __attribute__((ext_vector_type(8))) short bf16x8;
typedef __attribute__((ext_vector_type(4))) float f32x4;
typedef __attribute__((ext_vector_type(4))) short s16x4;

__device__ __forceinline__ float sigm(float v) {
  float e = __builtin_amdgcn_exp2f(-1.4426950408889634f * v);
  return __builtin_amdgcn_rcpf(1.0f + e);
}
__device__ __forceinline__ float tanh_f(float v) {
  float e = __builtin_amdgcn_exp2f(2.8853900817779268f * v);
  return 1.0f - 2.0f * __builtin_amdgcn_rcpf(1.0f + e);
}
// round-to-nearest-even bf16 hi/lo split: v ~= hi + lo (~16-bit mantissa coverage)
__device__ __forceinline__ void hilo(float v, short& h, short& l) {
  unsigned u = __builtin_bit_cast(unsigned, v);
  unsigned r = u + 0x7fffu + ((u >> 16) & 1u);
  h = (short)(r >> 16);
  float hf = __builtin_bit_cast(float, r & 0xffff0000u);
  float res = v - hf;
  unsigned u2 = __builtin_bit_cast(unsigned, res);
  unsigned r2 = u2 + 0x7fffu + ((u2 >> 16) & 1u);
  l = (short)(r2 >> 16);
}

// Barrier draining only LDS (lgkmcnt) — global output stores keep flowing.
__device__ __forceinline__ void barrier_lgkm() {
  asm volatile("s_waitcnt lgkmcnt(0)\n\ts_barrier" ::: "memory");
}

// two 8B-aligned ds_read_b64 -> one bf16x8 fragment
__device__ __forceinline__ bf16x8 read_h(const short* buf, int off) {
  s16x4 a = *(const s16x4*)(buf + off);
  s16x4 b = *(const s16x4*)(buf + off + 4);
  bf16x8 r;
  r[0]=a[0]; r[1]=a[1]; r[2]=a[2]; r[3]=a[3];
  r[4]=b[0]; r[5]=b[1]; r[6]=b[2]; r[7]=b[3];
  return r;
}

// gates in regs: g[0..3] = i,f,g,o for ONE (batch,unit) position
__device__ __forceinline__ float lstm_update(const f32x4& g, float& c) {
  float iv = sigm(g[0]), fv = sigm(g[1]), gv = tanh_f(g[2]), ov = sigm(g[3]);
  c = fv * c + iv * gv;
  return ov * tanh_f(c);
}

// Block: 512 threads = 8 waves, 16 batch rows, all T. 256 blocks = 1/CU.
// MFMA roles: A = weights (M = 16 gate-rows, interleaved m=(unit m>>2, gate m&3),
// wave w covers units 4w..4w+3), B = h (N = 16 batch rows). C layout (col=lane&15=batch,
// row=q*4+reg) => lane (n,q) holds gates i,f,g,o of (batch n, unit 4w+q) in its 4 regs:
// pointwise update is lane-local, no transpose.
// Pipelined: iteration t computes L1(t) and L2(t-1) (independent), ONE barrier/step.
__global__ __launch_bounds__(512, 2) void lstm_seq_kernel(
    const float* __restrict__ xg,
    const float* __restrict__ Wih1, const float* __restrict__ Whh1,
    const float* __restrict__ bih1, const float* __restrict__ bhh1,
    const float* __restrict__ Wih2, const float* __restrict__ Whh2,
    const float* __restrict__ bih2, const float* __restrict__ bhh2,
    const float* __restrict__ Wout, const float* __restrict__ bout,
    float* __restrict__ out)
{
  __shared__ __half xl[16 * 1028];                  // x staged fp16
  __shared__ short h1hiB[2][16 * HST], h1loB[2][16 * HST];  // ping-pong h buffers
  __shared__ short h2hiB[2][16 * HST], h2loB[2][16 * HST];

  const int tid  = threadIdx.x;
  const int w    = tid >> 6;     // wave 0..7
  const int lane = tid & 63;
  const int n    = lane & 15;    // A-row (weights) / B-col & C-col (batch) / update batch
  const int q    = lane >> 4;    // quad
  const int q4   = q * 4;
  const int q8   = q * 8;
  const int b0   = blockIdx.x * 16;
  const int p    = w & 1;        // out-proj tile (cols 16p..16p+15)

  // ---- stage x[b0..b0+15][0..1024) into LDS as fp16 (coalesced)
  for (int idx = tid; idx < 16 * 1024; idx += 512) {
    int row = idx >> 10, col = idx & 1023;
    xl[row * 1028 + col] = __float2half(xg[((size_t)(b0 + row) << 10) + col]);
  }

  // ---- weight A-fragments: A[m=lane&15][k=q8+j]; row m -> gate m&3, unit 4w+(m>>2)
  const int og = (n & 3) * HDIM + 4 * w + (n >> 2);
  bf16x8 Whh1h, Whh1l, Wih2h, Wih2l, Whh2h, Whh2l;
  #pragma unroll
  for (int j = 0; j < 8; j++) {
    short hh, ll;
    hilo(Whh1[og * HDIM + q8 + j], hh, ll); Whh1h[j] = hh; Whh1l[j] = ll;
    hilo(Wih2[og * HDIM + q8 + j], hh, ll); Wih2h[j] = hh; Wih2l[j] = ll;
    hilo(Whh2[og * HDIM + q8 + j], hh, ll); Whh2h[j] = hh; Whh2l[j] = ll;
  }
  // per-reg constants for the lane's update position (batch n, unit 4w+q), gate r
  float b1c[4], b2c[4], wx0[4], wx1[4], boc[4];
  #pragma unroll
  for (int r = 0; r < 4; r++) {
    int gr = r * HDIM + 4 * w + q;
    b1c[r] = bih1[gr] + bhh1[gr];
    b2c[r] = bih2[gr] + bhh2[gr];
    wx0[r] = Wih1[gr * 2 + 0];
    wx1[r] = Wih1[gr * 2 + 1];
    int orow = 16 * p + q4 + r;
    boc[r] = (orow < FOUT) ? bout[orow] : 0.0f;
  }
  // out-proj A-frag: row m -> out-row 16p+m (zero-padded past 19)
  bf16x8 WoH = {0,0,0,0,0,0,0,0}, WoL = {0,0,0,0,0,0,0,0};
  {
    int orow = 16 * p + n;
    if (orow < FOUT) {
      #pragma unroll
      for (int j = 0; j < 8; j++) {
        short hh, ll;
        hilo(Wout[orow * HDIM + q8 + j], hh, ll); WoH[j] = hh; WoL[j] = ll;
      }
    }
  }

  const int hoff = n * HST + 4 * w + q;  // write: (batch n, unit 4w+q)
  const int aoff = n * HST + q8;         // B-frag read: h[batch n][k=q8..q8+7]
  float c1 = 0.0f, c2 = 0.0f;

  bf16x8 h1h = {0,0,0,0,0,0,0,0}, h1l = {0,0,0,0,0,0,0,0};
  bf16x8 h2h = {0,0,0,0,0,0,0,0}, h2l = {0,0,0,0,0,0,0,0};

  __syncthreads();   // x staging visible (full barrier once)

  // ================= head: t = 0 (L1 only; h1(-1)=0 -> pure VALU, no MFMA)
  {
    __half2 hv = *(const __half2*)&xl[n * 1028];
    float xv0 = __half2float(hv.x), xv1 = __half2float(hv.y);
    f32x4 g1;
    #pragma unroll
    for (int r = 0; r < 4; r++) g1[r] = fmaf(xv1, wx1[r], fmaf(xv0, wx0[r], b1c[r]));
    float h1n = lstm_update(g1, c1);
    short hh, ll; hilo(h1n, hh, ll);
    h1hiB[0][hoff] = hh; h1loB[0][hoff] = ll;
    barrier_lgkm();
    h1h = read_h(h1hiB[0], aoff);
    h1l = read_h(h1loB[0], aoff);
  }

  // ================= main: iteration t computes L1(t) and L2(t-1)
  for (int t = 1; t < TLEN; ++t) {
    const int par = t & 1;
    // x(t)
    __half2 hv = *(const __half2*)&xl[n * 1028 + 2 * t];
    float xv0 = __half2float(hv.x), xv1 = __half2float(hv.y);

    // L1(t): b1 + x(t)@Wih1^T + Whh1 @ h1(t-1)   (3-product hi/lo)
    f32x4 g1;
    #pragma unroll
    for (int r = 0; r < 4; r++) g1[r] = fmaf(xv1, wx1[r], fmaf(xv0, wx0[r], b1c[r]));
    g1 = __builtin_amdgcn_mfma_f32_16x16x32_bf16(Whh1h, h1h, g1, 0, 0, 0);
    g1 = __builtin_amdgcn_mfma_f32_16x16x32_bf16(Whh1l, h1h, g1, 0, 0, 0);
    g1 = __builtin_amdgcn_mfma_f32_16x16x32_bf16(Whh1h, h1l, g1, 0, 0, 0);

    // L2(t-1): b2 + Wih2 @ h1(t-1) + Whh2 @ h2(t-2)  (two independent chains)
    f32x4 ga, gb;
    #pragma unroll
    for (int r = 0; r < 4; r++) { ga[r] = b2c[r]; gb[r] = 0.0f; }
    ga = __builtin_amdgcn_mfma_f32_16x16x32_bf16(Wih2h, h1h, ga, 0, 0, 0);
    gb = __builtin_amdgcn_mfma_f32_16x16x32_bf16(Whh2h, h2h, gb, 0, 0, 0);
    ga = __builtin_amdgcn_mfma_f32_16x16x32_bf16(Wih2l, h1h, ga, 0, 0, 0);
    gb = __builtin_amdgcn_mfma_f32_16x16x32_bf16(Whh2l, h2h, gb, 0, 0, 0);
    ga = __builtin_amdgcn_mfma_f32_16x16x32_bf16(Wih2h, h1l, ga, 0, 0, 0);
    gb = __builtin_amdgcn_mfma_f32_16x16x32_bf16(Whh2h, h2l, gb, 0, 0, 0);

    // pointwise updates (lane-local, independent chains)
    float h1n = lstm_update(g1, c1);
    f32x4 g2;
    #pragma unroll
    for (int r = 0; r < 4; r++) g2[r] = ga[r] + gb[r];
    float h2n = lstm_update(g2, c2);

    short hh, ll;
    hilo(h1n, hh, ll); h1hiB[par][hoff] = hh; h1loB[par][hoff] = ll;
    hilo(h2n, hh, ll); h2hiB[par][hoff] = hh; h2loB[par][hoff] = ll;

    barrier_lgkm();   // h1(t), h2(t-1) visible

    h1h = read_h(h1hiB[par], aoff);
    h1l = read_h(h1loB[par], aoff);
    h2h = read_h(h2hiB[par], aoff);
    h2l = read_h(h2loB[par], aoff);

    // out-proj step s=t-1, rotated across wave pairs (3 MFMAs per wave per 4 steps)
    const int s = t - 1;
    if ((w >> 1) == (s & 3)) {
      f32x4 ao;
      #pragma unroll
      for (int r = 0; r < 4; r++) ao[r] = boc[r];
      ao = __builtin_amdgcn_mfma_f32_16x16x32_bf16(WoH, h2h, ao, 0, 0, 0);
      ao = __builtin_amdgcn_mfma_f32_16x16x32_bf16(WoL, h2h, ao, 0, 0, 0);
      ao = __builtin_amdgcn_mfma_f32_16x16x32_bf16(WoH, h2l, ao, 0, 0, 0);
      if (p == 0 || q == 0) {
        float4 st = { ao[0], ao[1], ao[2], ao[3] };
        *(float4*)&out[((size_t)(b0 + n) * TLEN + s) * FOUT + 16 * p + q4] = st;
      }
    }
  }

  // ================= tail: L2(511) + out(511)
  {
    f32x4 ga, gb;
    #pragma unroll
    for (int r = 0; r < 4; r++) { ga[r] = b2c[r]; gb[r] = 0.0f; }
    ga = __builtin_amdgcn_mfma_f32_16x16x32_bf16(Wih2h, h1h, ga, 0, 0, 0);
    gb = __builtin_amdgcn_mfma_f32_16x16x32_bf16(Whh2h, h2h, gb, 0, 0, 0);
    ga = __builtin_amdgcn_mfma_f32_16x16x32_bf16(Wih2l, h1h, ga, 0, 0, 0);
    gb = __builtin_amdgcn_mfma_f32_16x16x32_bf16(Whh2l, h2h, gb, 0, 0, 0);
    ga = __builtin_amdgcn_mfma_f32_16x16x32_bf16(Wih2h, h1l, ga, 0, 0, 0);
    gb = __builtin_amdgcn_mfma_f32_16x16x32_bf16(Whh2h, h2l, gb, 0, 0, 0);
    f32x4 g2;
    #pragma unroll
    for (int r = 0; r < 4; r++) g2[r] = ga[r] + gb[r];
    float h2n = lstm_update(g2, c2);
    short hh, ll; hilo(h2n, hh, ll);
    h2hiB[0][hoff] = hh; h2loB[0][hoff] = ll;
    barrier_lgkm();
    h2h = read_h(h2hiB[0], aoff);
    h2l = read_h(h2loB[0], aoff);
    const int s = TLEN - 1;          // 511; 511&3==3 -> waves 6,7
    if ((w >> 1) == (s & 3)) {
      f32x4 ao;
      #pragma unroll
      for (int r = 0; r < 4; r++) ao[r] = boc[r];
      ao = __builtin_amdgcn_mfma_f32_16x16x32_bf16(WoH, h2h, ao, 0, 0, 0);
      ao = __builtin_amdgcn_mfma_f32_16x16x32_bf16(WoL, h2h, ao, 0, 0, 0);
      ao = __builtin_amdgcn_mfma_f32_16x16x32_bf16(WoH, h2l, ao, 0, 0, 0);
      if (p == 0 || q == 0) {
        float4 st = { ao[0], ao[1], ao[2], ao[3] };
        *(float4*)&out[((size_t)(b0 + n) * TLEN + s) * FOUT + 16 * p + q4] = st;
      }
    }
  }
}

extern "C" void kernel_launch(void* const* d_in, const int* in_sizes, int n_in,
                              void* d_out, int out_size, void* d_ws, size_t ws_size,
                              hipStream_t stream) {
  const float* xg   = (const float*)d_in[0];
  const float* Wih1 = (const float*)d_in[1];
  const float* Whh1 = (const float*)d_in[2];
  const float* bih1 = (const float*)d_in[3];
  const float* bhh1 = (const float*)d_in[4];
  const float* Wih2 = (const float*)d_in[5];
  const float* Whh2 = (const float*)d_in[6];
  const float* bih2 = (const float*)d_in[7];
  const float* bhh2 = (const float*)d_in[8];
  const float* Wout = (const float*)d_in[9];
  const float* bout = (const float*)d_in[10];
  float* out = (float*)d_out;

  hipLaunchKernelGGL(lstm_seq_kernel, dim3(256), dim3(512), 0, stream,
                     xg, Wih1, Whh1, bih1, bhh1, Wih2, Whh2, bih2, bhh2, Wout, bout, out);
}